// Round 1
// 373.985 us; speedup vs baseline: 1.6526x; 1.6526x over previous
//
#include <hip/hip_runtime.h>
#include <cstdint>
#include <cstddef>

// EEG_SimpleLSM round 7: vectorized, latency-clustered x loader.
// R6 post-mortem: rewriting reduces (300->~4 cyc/step) and deepening update
// prefetch (2->8) moved the bench 615.2 -> 618.0 us, i.e. ZERO. The critical
// stage is therefore neither; phase time is 17.1k cyc (484us/68 phases) and
// the only stage untouched across rounds is the loader. Its per-channel
//   dst[lane*33+k] = ok ? xb[k*T+tg] : 0.f
// pattern (conditional load feeding an immediate ds_write, x32, inside a
// wave-divergence-capable branch) is exactly what defeats hipcc's global-load
// clustering: 32 serialized ~500-600cyc L3/HBM round-trips ~= 16-19k cyc ==
// the measured phase time.
// Fix: 8 independent global_load_dwordx4 (lane = (ch sub-idx, 4 t's)) issued
// back-to-back into a register array with NO intervening DS ops, addresses
// clamped in-bounds (mask applied at the LDS write; rows >= S are never read
// by L0u anyway), then 32 conflict-free ds_write_b32 (bank ids 4m+g4 cover
// 0..63 -> 2-way alias = free). Exposed latency: ~one round-trip per phase.
// Everything else byte-identical to R6.
// Waves (512 thr): w6 loader(p) | w0 L0u(p-1) | w1 L0r(p-2) | w2 L1u(p-3) |
// w3/w7 L1r lo/hi(p-4) | w4/w5 L2 rows 0-63/64-127 (p-5). Depth-5 pipeline,
// double-buffered rings, one __syncthreads per phase (wave-uniform branches).
// Arithmetic identical to rounds 1-6 (absmax 0.0): fmaf charge with flag in
// {0,1} (exact), /3 via exact f64 multiply (see R6 proof), reciprocal-mul for
// /80000, unmasked per-lane reset.

#pragma clang fp contract(off)

constexpr int T_TOTAL = 4000;
constexpr int NCH = 32;
constexpr int N1 = 64;
constexpr int N2 = 128;
constexpr int CT = 64;
constexpr int XSS = NCH + 1;                      // 33
constexpr int NCHUNK = (T_TOTAL + CT - 1) / CT;   // 63 (last chunk = 32 steps)

__device__ __forceinline__ int read_lane_i(int v, int l) {
  return __builtin_amdgcn_readlane(v, l);
}

__global__ __launch_bounds__(512, 1) void lsm_kernel(
    const float* __restrict__ x, const float* __restrict__ W1,
    const float* __restrict__ W2, float* __restrict__ out) {
  __shared__ float w1s[N1 * 33];        // W1[n][k] at n*33+k
  __shared__ float w2s[N2 * 65];        // W2[n][k] at n*65+k
  __shared__ float xs[2][CT * XSS];     // x chunk, [time][ch], stride 33
  __shared__ float nv0r[2][CT * 33];    // L0 nv ring, [step][neuron<32]
  __shared__ float nv1r[2][CT * 65];    // L1 nv ring, [step][neuron<64]
  __shared__ unsigned j0r[2][CT];       // L0 (spike<<8)|argmax per step
  __shared__ float mpr[2][2][CT];       // L1 partial max  [parity][half][step]
  __shared__ int   jpr[2][2][CT];       // L1 partial argj [parity][half][step]

  const int tid = threadIdx.x;
  const int wid = tid >> 6;
  const int lane = tid & 63;
  const int b = blockIdx.x;

  for (int e = tid; e < N1 * NCH; e += 512) w1s[(e >> 5) * 33 + (e & 31)] = W1[e];
  for (int e = tid; e < N2 * N1; e += 512) w2s[(e >> 6) * 65 + (e & 63)] = W2[e];
  __syncthreads();

  const float* xb = x + (size_t)b * (NCH * T_TOTAL);

  // Persistent per-wave state.
  float v0 = 0.f, d0 = 0.f;          // w0
  float v1 = 0.f;                    // w2
  float v2 = 0.f, pv2 = 0.f;         // w4 (rows 0-63) / w5 (rows 64-127)

  for (int p = 0; p < NCHUNK + 5; ++p) {
    if (wid == 6) {
      // ---------- loader: x chunk p -> xs, transposed, dwordx4 ----------
      const int c = p;
      if (c < NCHUNK) {
        float* dst = xs[c & 1];
        const int g4 = lane >> 4;            // channel sub-index 0..3
        const int tl = (lane & 15) << 2;     // local t: 0,4,...,60
        const int tg = c * CT + tl;          // global t of first element
        const bool ok = (tg + 3) < T_TOTAL;  // all-4 valid (T_TOTAL % 4 == 0)
        const int tgs = ok ? tg : 0;         // clamped, always in-bounds
        float4 vr[8];
        // Phase A: 8 independent 16B loads, no DS ops between -> all in
        // flight together; one memory round-trip of exposed latency.
#pragma unroll
        for (int g = 0; g < 8; ++g) {
          const int k = g * 4 + g4;
          vr[g] = *reinterpret_cast<const float4*>(&xb[(size_t)k * T_TOTAL + tgs]);
        }
        // Phase B: 32 ds_write_b32; banks (4m+g4+const)%32 -> 2-way = free.
        // Rows >= S are never read by L0u, but zero them anyway (hygiene).
#pragma unroll
        for (int g = 0; g < 8; ++g) {
          const int k = g * 4 + g4;
          dst[(tl + 0) * XSS + k] = ok ? vr[g].x : 0.f;
          dst[(tl + 1) * XSS + k] = ok ? vr[g].y : 0.f;
          dst[(tl + 2) * XSS + k] = ok ? vr[g].z : 0.f;
          dst[(tl + 3) * XSS + k] = ok ? vr[g].w : 0.f;
        }
      }
    } else if (wid == 0) {
      // ---------- L0 update (chunk p-1): carried chain ----------
      const int c = p - 1;
      if (c >= 0 && c < NCHUNK) {
        const float* xsb = xs[c & 1];
        float* nvd = nv0r[c & 1];
        const int S = min(CT, T_TOTAL - c * CT);
        const int xl = lane & 31;       // lanes 32-63 mirror 0-31 (same-value
                                        // dup LDS writes: harmless, 2-way)
        float xr[8];
#pragma unroll
        for (int k = 0; k < 8; ++k) xr[k] = xsb[k * XSS + xl];
        for (int tb = 0; tb < S; tb += 8) {
#pragma unroll
          for (int k = 0; k < 8; ++k) {
            const int tt = tb + k;
            float xc = xr[k];
            int tn = tt + 8; tn = (tn < S) ? tn : S - 1;   // depth-8 prefetch
            xr[k] = xsb[tn * XSS + xl];
            float nv0 = (v0 + xc) - d0;
            double q = (double)nv0 * (1.0 / 3.0);
            float dn = (float)q;        // == RN32(nv0/3) — see R6 proof
            bool r = nv0 >= 1.5f;
            v0 = r ? 0.f : nv0;
            d0 = r ? 0.f : dn;          // 0/3 = +0 exact
            nvd[tt * 33 + xl] = nv0;    // off-chain stream-out
          }
        }
      }
    } else if (wid == 1) {
      // ---------- L0 reduce (chunk p-2): lane = step, scan 32 neurons ----
      const int c = p - 2;
      if (c >= 0 && c < NCHUNK) {
        const float* nvs = nv0r[c & 1] + lane * 33;
        float m = nvs[0];
        int j = 0;
#pragma unroll 8
        for (int n = 1; n < 32; ++n) {
          float v = nvs[n];
          bool g = v > m;               // strict: first index kept on ties
          j = g ? n : j;
          m = g ? v : m;
        }
        // lanes >= S hold garbage from stale ring rows: finite, never read.
        j0r[c & 1][lane] = (unsigned)j | ((m >= 1.5f) ? 0x100u : 0u);
      }
    } else if (wid == 2) {
      // ---------- L1 update (chunk p-3) ----------
      const int c = p - 3;
      if (c >= 0 && c < NCHUNK) {
        const int S = min(CT, T_TOTAL - c * CT);
        const int jv = (int)j0r[c & 1][lane];
        float* nvd = nv1r[c & 1];
        const int base1 = lane * 33;
        float hr[8], fr[8];
#pragma unroll
        for (int k = 0; k < 8; ++k) {
          int pk = read_lane_i(jv, k);
          hr[k] = w1s[base1 + (pk & 0xFF)];
          fr[k] = (pk & 0x100) ? 1.f : 0.f;
        }
        for (int tb = 0; tb < S; tb += 8) {
#pragma unroll
          for (int k = 0; k < 8; ++k) {
            const int tt = tb + k;
            float h = hr[k], f = fr[k];
            int tn = tt + 8; tn = (tn < S) ? tn : S - 1;   // depth-8 prefetch
            int pk = read_lane_i(jv, tn);
            hr[k] = w1s[base1 + (pk & 0xFF)];
            fr[k] = (pk & 0x100) ? 1.f : 0.f;
            float nv1 = __builtin_fmaf(h, f, v1) - v1 * (1.0f / 80000.0f);
            v1 = (nv1 >= 1.2f) ? 0.f : nv1;   // per-lane unmasked reset
            nvd[tt * 65 + lane] = nv1;
          }
        }
      }
    } else if (wid == 3 || wid == 7) {
      // ---------- L1 reduce (chunk p-4): lane = step, neuron half-scan ----
      const int c = p - 4;
      if (c >= 0 && c < NCHUNK) {
        const int half = (wid == 7) ? 1 : 0;
        const float* nvs = nv1r[c & 1] + lane * 65 + half * 32;
        float m = nvs[0];
        int j = 0;
#pragma unroll 8
        for (int n = 1; n < 32; ++n) {
          float v = nvs[n];
          bool g = v > m;
          j = g ? n : j;
          m = g ? v : m;
        }
        mpr[c & 1][half][lane] = m;
        jpr[c & 1][half][lane] = j;
      }
    } else {
      // ---------- L2 update (chunk p-5): w4 rows 0-63, w5 rows 64-127 ----
      const int c = p - 5;
      if (c >= 0 && c < NCHUNK) {
        const int S = min(CT, T_TOTAL - c * CT);
        // merge L1 partials per-lane (lane = step); tie -> low half = first idx
        float mlo = mpr[c & 1][0][lane], mhi = mpr[c & 1][1][lane];
        int jlo = jpr[c & 1][0][lane], jhi = jpr[c & 1][1][lane];
        bool g = mhi > mlo;
        float mm = g ? mhi : mlo;
        int jj = g ? (jhi + 32) : jlo;
        const int pkv = jj | ((mm >= 1.2f) ? 0x100 : 0);
        const int wbase = (lane + ((wid == 5) ? 64 : 0)) * 65;
        float hr[8], fr[8];
#pragma unroll
        for (int k = 0; k < 8; ++k) {
          int pk = read_lane_i(pkv, k);
          hr[k] = w2s[wbase + (pk & 0xFF)];
          fr[k] = (pk & 0x100) ? 1.f : 0.f;
        }
        for (int tb = 0; tb < S; tb += 8) {
#pragma unroll
          for (int k = 0; k < 8; ++k) {
            const int tt = tb + k;
            float h = hr[k], f = fr[k];
            int tn = tt + 8; tn = (tn < S) ? tn : S - 1;   // depth-8 prefetch
            int pk = read_lane_i(pkv, tn);
            hr[k] = w2s[wbase + (pk & 0xFF)];
            fr[k] = (pk & 0x100) ? 1.f : 0.f;
            float nv2 = __builtin_fmaf(h, f, v2) - v2 * (1.0f / 80000.0f);
            pv2 = nv2;                  // pre-reset membrane
            v2 = (nv2 >= 1.2f) ? 0.f : nv2;
          }
        }
      }
    }
    __syncthreads();  // wave-uniform branches: all 8 waves always arrive
  }

  if (wid == 4) out[(size_t)b * N2 + lane] = expf(pv2);
  if (wid == 5) out[(size_t)b * N2 + 64 + lane] = expf(pv2);
}

extern "C" void kernel_launch(void* const* d_in, const int* in_sizes, int n_in,
                              void* d_out, int out_size, void* d_ws, size_t ws_size,
                              hipStream_t stream) {
  (void)n_in; (void)out_size; (void)d_ws; (void)ws_size;
  const float* x = (const float*)d_in[0];
  const float* W1 = (const float*)d_in[1];
  const float* W2 = (const float*)d_in[2];
  float* out = (float*)d_out;
  const int B = in_sizes[0] / (NCH * T_TOTAL);  // 256
  lsm_kernel<<<dim3(B), dim3(512), 0, stream>>>(x, W1, W2, out);
}

// Round 2
// 308.060 us; speedup vs baseline: 2.0063x; 1.2140x over previous
//
#include <hip/hip_runtime.h>
#include <cstdint>
#include <cstddef>

// EEG_SimpleLSM round 8: SIMD load balancing + per-step VALU diet.
// R7 post-mortem: loader fix confirmed (484->244us, VALUBusy 17->33%). Now
// phase = 8.6k cyc; no stage chain explains it, but VALU-issue accounting
// does: update stages issue ~1-2k wave64 VALU instrs/phase each, and with
// round-robin wave->SIMD mapping the old wid layout put L0u+L2a (two
// heaviest) on the same SIMD (~7-8k issue-cyc incl. addressing overhead)
// while the reduce SIMD idled. Barrier waits for the worst SIMD.
// Fixes:
//  (1) Stage->wid remap H,L,H,L,L,H,L,H: mixed heavy/light under BOTH
//      plausible mappings (SIMD=wid%4 and SIMD=wid>>1).
//      w0=L0u w1=L0r w2=L1u w3=L1r-lo w4=loader w5=L2a w6=L1r-hi w7=L2b.
//  (2) Prefetch clamp removed (cmp+cndmask per step x4 waves): rings padded
//      to 72 rows so tt+8 always reads in-bounds; pad rows are garbage bits
//      loaded into regs but never arithmetically consumed (S%8==0 makes the
//      last block's prefetches dead). readlane idx &63 wraps: stale-but-
//      bounded values (j0r always in [0,32], pkv in [0,64]) -> gathers stay
//      in-bounds; dead anyway.
//  (3) Zero-column gather: w1s col 32 = 0, w2s col 64 = 0; reduces store
//      (spike ? j : ZERO_COL). Kills per-step fr select; charge becomes
//      (v + h) - v*rcp. Exact: v+0=v; v+w == fma(w,1,v) (single rounding).
//  (4) Constant-offset pointer loops -> ds ops use immediate offsets, no
//      per-step address VALU.
// Waves (512 thr): w4 loader(p) | w0 L0u(p-1) | w1 L0r(p-2) | w2 L1u(p-3) |
// w3/w6 L1r lo/hi(p-4) | w5/w7 L2 rows 0-63/64-127 (p-5). Depth-5 pipeline,
// double-buffered rings, one __syncthreads per phase (wave-uniform branches).
// Arithmetic identical to rounds 1-7 (absmax 0.0): add-charge with
// zero-column (exact), /3 via exact f64 multiply (R6 proof), reciprocal-mul
// for /80000, unmasked per-lane reset.

#pragma clang fp contract(off)

constexpr int T_TOTAL = 4000;
constexpr int NCH = 32;
constexpr int N1 = 64;
constexpr int N2 = 128;
constexpr int CT = 64;
constexpr int CTP = CT + 8;                       // 72: prefetch-safe rows
constexpr int XSS = NCH + 1;                      // 33
constexpr int NCHUNK = (T_TOTAL + CT - 1) / CT;   // 63 (last chunk = 32 steps)

__device__ __forceinline__ int read_lane_i(int v, int l) {
  return __builtin_amdgcn_readlane(v, l);
}

__global__ __launch_bounds__(512, 1) void lsm_kernel(
    const float* __restrict__ x, const float* __restrict__ W1,
    const float* __restrict__ W2, float* __restrict__ out) {
  __shared__ float w1s[N1 * 33];        // W1[n][k] at n*33+k; col 32 == 0
  __shared__ float w2s[N2 * 65];        // W2[n][k] at n*65+k; col 64 == 0
  __shared__ float xs[2][CTP * XSS];    // x chunk, [time][ch], stride 33
  __shared__ float nv0r[2][CTP * 33];   // L0 nv ring, [step][neuron<32]
  __shared__ float nv1r[2][CTP * 65];   // L1 nv ring, [step][neuron<64]
  __shared__ unsigned j0r[2][CT];       // L0 gather idx (32 = no spike)
  __shared__ float mpr[2][2][CT];       // L1 partial max  [parity][half][step]
  __shared__ int   jpr[2][2][CT];       // L1 partial argj [parity][half][step]

  const int tid = threadIdx.x;
  const int wid = tid >> 6;
  const int lane = tid & 63;
  const int b = blockIdx.x;

  for (int e = tid; e < N1 * NCH; e += 512) w1s[(e >> 5) * 33 + (e & 31)] = W1[e];
  for (int e = tid; e < N2 * N1; e += 512) w2s[(e >> 6) * 65 + (e & 63)] = W2[e];
  if (tid < N1) w1s[tid * 33 + 32] = 0.f;          // zero column
  if (tid < N2) w2s[tid * 65 + 64] = 0.f;          // zero column
  __syncthreads();

  const float* xb = x + (size_t)b * (NCH * T_TOTAL);

  // Persistent per-wave state.
  float v0 = 0.f, d0 = 0.f;          // w0
  float v1 = 0.f;                    // w2
  float v2 = 0.f, pv2 = 0.f;         // w5 (rows 0-63) / w7 (rows 64-127)

  for (int p = 0; p < NCHUNK + 5; ++p) {
    if (wid == 0) {
      // ---------- L0 update (chunk p-1): the f64 carried chain ----------
      const int c = p - 1;
      if (c >= 0 && c < NCHUNK) {
        const int S = min(CT, T_TOTAL - c * CT);
        const int xl = lane & 31;       // lanes 32-63 mirror 0-31
        const float* xcol = xs[c & 1] + xl;
        float* ncol = nv0r[c & 1] + xl;
        float xr[8];
#pragma unroll
        for (int k = 0; k < 8; ++k) xr[k] = xcol[k * XSS];
        for (int tb = 0; tb < S; tb += 8) {
          const float* xp = xcol + (tb + 8) * XSS;   // prefetch rows (pad-safe)
          float* np = ncol + tb * 33;
#pragma unroll
          for (int k = 0; k < 8; ++k) {
            float xc = xr[k];
            xr[k] = xp[k * XSS];        // depth-8 prefetch, immediate offset
            float nv0 = (v0 + xc) - d0;
            double q = (double)nv0 * (1.0 / 3.0);
            float dn = (float)q;        // == RN32(nv0/3) — see R6 proof
            bool r = nv0 >= 1.5f;
            v0 = r ? 0.f : nv0;
            d0 = r ? 0.f : dn;          // 0/3 = +0 exact
            np[k * 33] = nv0;           // off-chain stream-out
          }
        }
      }
    } else if (wid == 1) {
      // ---------- L0 reduce (chunk p-2): lane = step, scan 32 neurons ----
      const int c = p - 2;
      if (c >= 0 && c < NCHUNK) {
        const float* nvs = nv0r[c & 1] + lane * 33;
        float m = nvs[0];
        int j = 0;
#pragma unroll 8
        for (int n = 1; n < 32; ++n) {
          float v = nvs[n];
          bool g = v > m;               // strict: first index kept on ties
          j = g ? n : j;
          m = g ? v : m;
        }
        // lanes >= S hold stale ring rows: finite, never consumed.
        j0r[c & 1][lane] = (m >= 1.5f) ? (unsigned)j : 32u;  // 32 -> zero col
      }
    } else if (wid == 2) {
      // ---------- L1 update (chunk p-3) ----------
      const int c = p - 3;
      if (c >= 0 && c < NCHUNK) {
        const int S = min(CT, T_TOTAL - c * CT);
        const int jv = (int)j0r[c & 1][lane];
        const float* wrow = w1s + lane * 33;
        float* ncol = nv1r[c & 1] + lane;
        float hr[8];
#pragma unroll
        for (int k = 0; k < 8; ++k) hr[k] = wrow[read_lane_i(jv, k)];
        for (int tb = 0; tb < S; tb += 8) {
          float* np = ncol + tb * 65;
#pragma unroll
          for (int k = 0; k < 8; ++k) {
            float h = hr[k];
            hr[k] = wrow[read_lane_i(jv, (tb + k + 8) & 63)];  // wraps: dead
            float nv1 = (v1 + h) - v1 * (1.0f / 80000.0f);
            v1 = (nv1 >= 1.2f) ? 0.f : nv1;   // per-lane unmasked reset
            np[k * 65] = nv1;
          }
        }
      }
    } else if (wid == 3 || wid == 6) {
      // ---------- L1 reduce (chunk p-4): lane = step, neuron half-scan ----
      const int c = p - 4;
      if (c >= 0 && c < NCHUNK) {
        const int half = (wid == 6) ? 1 : 0;
        const float* nvs = nv1r[c & 1] + lane * 65 + half * 32;
        float m = nvs[0];
        int j = 0;
#pragma unroll 8
        for (int n = 1; n < 32; ++n) {
          float v = nvs[n];
          bool g = v > m;
          j = g ? n : j;
          m = g ? v : m;
        }
        mpr[c & 1][half][lane] = m;
        jpr[c & 1][half][lane] = j;
      }
    } else if (wid == 4) {
      // ---------- loader: x chunk p -> xs, transposed, dwordx4 ----------
      const int c = p;
      if (c < NCHUNK) {
        float* dst = xs[c & 1];
        const int g4 = lane >> 4;            // channel sub-index 0..3
        const int tl = (lane & 15) << 2;     // local t: 0,4,...,60
        const int tg = c * CT + tl;          // global t of first element
        const bool ok = (tg + 3) < T_TOTAL;  // all-4 valid (T_TOTAL % 4 == 0)
        const int tgs = ok ? tg : 0;         // clamped, always in-bounds
        float4 vr[8];
        // Phase A: 8 independent 16B loads, no DS ops between -> all in
        // flight together; one memory round-trip of exposed latency.
#pragma unroll
        for (int g = 0; g < 8; ++g) {
          const int k = g * 4 + g4;
          vr[g] = *reinterpret_cast<const float4*>(&xb[(size_t)k * T_TOTAL + tgs]);
        }
        // Phase B: 32 ds_write_b32; 2-way bank alias = free (m136).
#pragma unroll
        for (int g = 0; g < 8; ++g) {
          const int k = g * 4 + g4;
          dst[(tl + 0) * XSS + k] = ok ? vr[g].x : 0.f;
          dst[(tl + 1) * XSS + k] = ok ? vr[g].y : 0.f;
          dst[(tl + 2) * XSS + k] = ok ? vr[g].z : 0.f;
          dst[(tl + 3) * XSS + k] = ok ? vr[g].w : 0.f;
        }
      }
    } else {
      // ---------- L2 update (chunk p-5): w5 rows 0-63, w7 rows 64-127 ----
      const int c = p - 5;
      if (c >= 0 && c < NCHUNK) {
        const int S = min(CT, T_TOTAL - c * CT);
        // merge L1 partials per-lane (lane = step); tie -> low half = first idx
        float mlo = mpr[c & 1][0][lane], mhi = mpr[c & 1][1][lane];
        int jlo = jpr[c & 1][0][lane], jhi = jpr[c & 1][1][lane];
        bool g = mhi > mlo;
        float mm = g ? mhi : mlo;
        int jj = g ? (jhi + 32) : jlo;
        const int pkv = (mm >= 1.2f) ? jj : 64;          // 64 -> zero col
        const float* wrow = w2s + (lane + ((wid == 7) ? 64 : 0)) * 65;
        float hr[8];
#pragma unroll
        for (int k = 0; k < 8; ++k) hr[k] = wrow[read_lane_i(pkv, k)];
        for (int tb = 0; tb < S; tb += 8) {
#pragma unroll
          for (int k = 0; k < 8; ++k) {
            float h = hr[k];
            hr[k] = wrow[read_lane_i(pkv, (tb + k + 8) & 63)];  // wraps: dead
            float nv2 = (v2 + h) - v2 * (1.0f / 80000.0f);
            pv2 = nv2;                  // pre-reset membrane
            v2 = (nv2 >= 1.2f) ? 0.f : nv2;
          }
        }
      }
    }
    __syncthreads();  // wave-uniform branches: all 8 waves always arrive
  }

  if (wid == 5) out[(size_t)b * N2 + lane] = expf(pv2);
  if (wid == 7) out[(size_t)b * N2 + 64 + lane] = expf(pv2);
}

extern "C" void kernel_launch(void* const* d_in, const int* in_sizes, int n_in,
                              void* d_out, int out_size, void* d_ws, size_t ws_size,
                              hipStream_t stream) {
  (void)n_in; (void)out_size; (void)d_ws; (void)ws_size;
  const float* x = (const float*)d_in[0];
  const float* W1 = (const float*)d_in[1];
  const float* W2 = (const float*)d_in[2];
  float* out = (float*)d_out;
  const int B = in_sizes[0] / (NCH * T_TOTAL);  // 256
  lsm_kernel<<<dim3(B), dim3(512), 0, stream>>>(x, W1, W2, out);
}

// Round 3
// 302.250 us; speedup vs baseline: 2.0448x; 1.0192x over previous
//
#include <hip/hip_runtime.h>
#include <cstdint>
#include <cstddef>

// EEG_SimpleLSM round 9: carried-select folding + Markstein /3 + [n][t]
// b128-batched rings.
// R8 post-mortem: 244->182us, VALUBusy 42%. Phase = 6.4k cyc = 100 cyc/step;
// issue floor ~2.7k/SIMD -> ~55% of worst-SIMD time is stall: carried-chain
// latency (L0 f64 divide ~24-32 cyc/step) + DS latency exposure (depth-8 b32
// prefetch queues 16 DS ops > lgkmcnt max 15 -> conservative waits) + 2
// DS-ops/step/wave keeping the in-order lgkm queue deep.
// Fixes:
//  (1) Carried-select folding: carry ONLY pre-reset membrane nvp.
//      nv' = r ? x : (RN(nvp+x) - RN(nvp/3)), r = nvp>=th. Bit-identical to
//      reference (reset case: RN(0+x)=x, RN(x-0)=x; RN(0*c)=+0; x never -0
//      from jax.random.normal). Chain: L0 32->20, L1/L2 16->12 cyc/step.
//  (2) Markstein exact f32 /3: q0=nvp*r3; e=fmaf(-3,q0,nvp); q=fmaf(e,r3,q0)
//      == RN(nvp/3) for all normal nvp (division-residual exactness lemma +
//      Markstein's theorem, RN mode; explicit fmaf, contract(off) safe).
//      -0 corner unreachable: nvp=-0 requires x=-0, impossible.
//  (3) Rings relayout to [neuron][step]: nv0r/nv1r stride 76 (12 mod 32 ->
//      8 distinct bank-quads per 8 lanes = min-time b128), xs stride 92
//      (28 mod 32, room for +24-step prefetch overrun). Updates write nv via
//      ds_write_b128 (L0: lanes<32 pack steps t..t+3, lanes>=32 pack t+4..t+7
//      -> 1 write/lane/8-block; L1: 2 writes/lane), L0u reads x via
//      ds_read_b128 (mirror lanes broadcast = free), loader writes 8 b128.
//      DS ops/phase drop ~3x; lgkm queue stays < 15 so counted waits hide
//      the ~120cyc DS latency. Reduces read [n][t] lane-contiguous (2-way =
//      free).
// Waves (512 thr): w4 loader(p) | w0 L0u(p-1) | w1 L0r(p-2) | w2 L1u(p-3) |
// w3/w6 L1r lo/hi(p-4) | w5/w7 L2 rows 0-63/64-127 (p-5). Depth-5 pipeline,
// double-buffered rings, one __syncthreads per phase (wave-uniform branches).

#pragma clang fp contract(off)

constexpr int T_TOTAL = 4000;
constexpr int NCH = 32;
constexpr int N1 = 64;
constexpr int N2 = 128;
constexpr int CT = 64;
constexpr int TS0 = 92;                           // xs [ch][t] stride
constexpr int TS1 = 76;                           // nv rings [n][t] stride
constexpr int NCHUNK = (T_TOTAL + CT - 1) / CT;   // 63 (last chunk = 32 steps)

__device__ __forceinline__ int read_lane_i(int v, int l) {
  return __builtin_amdgcn_readlane(v, l);
}

__global__ __launch_bounds__(512, 1) void lsm_kernel(
    const float* __restrict__ x, const float* __restrict__ W1,
    const float* __restrict__ W2, float* __restrict__ out) {
  __shared__ float w1s[N1 * 33];        // W1[n][k] at n*33+k; col 32 == 0
  __shared__ float w2s[N2 * 65];        // W2[n][k] at n*65+k; col 64 == 0
  __shared__ float xs[2][NCH * TS0];    // x chunk, [ch][t]
  __shared__ float nv0r[2][NCH * TS1];  // L0 nv ring, [neuron][t]
  __shared__ float nv1r[2][N1 * TS1];   // L1 nv ring, [neuron][t]
  __shared__ unsigned j0r[2][CT];       // L0 gather idx (32 = zero col)
  __shared__ float mpr[2][2][CT];       // L1 partial max  [parity][half][step]
  __shared__ int   jpr[2][2][CT];       // L1 partial argj [parity][half][step]

  const int tid = threadIdx.x;
  const int wid = tid >> 6;
  const int lane = tid & 63;
  const int b = blockIdx.x;

  for (int e = tid; e < N1 * NCH; e += 512) w1s[(e >> 5) * 33 + (e & 31)] = W1[e];
  for (int e = tid; e < N2 * N1; e += 512) w2s[(e >> 6) * 65 + (e & 63)] = W2[e];
  if (tid < N1) w1s[tid * 33 + 32] = 0.f;          // zero column
  if (tid < N2) w2s[tid * 65 + 64] = 0.f;          // zero column
  __syncthreads();

  const float* xb = x + (size_t)b * (NCH * T_TOTAL);
  constexpr float R3 = 1.0f / 3.0f;                // RN(1/3)
  constexpr float R80 = 1.0f / 80000.0f;

  // Persistent per-wave state: pre-reset membranes.
  float nv0p = 0.f;                  // w0
  float nv1p = 0.f;                  // w2
  float nv2p = 0.f;                  // w5 (rows 0-63) / w7 (rows 64-127)

  for (int p = 0; p < NCHUNK + 5; ++p) {
    if (wid == 0) {
      // ---------- L0 update (chunk p-1): the carried chain ----------
      const int c = p - 1;
      if (c >= 0 && c < NCHUNK) {
        const int S = min(CT, T_TOTAL - c * CT);
        const int xl = lane & 31;
        const int hi4 = (lane >> 5) << 2;          // 0 | 4: write-half offset
        const float* xrow = xs[c & 1] + xl * TS0;  // mirror lanes: broadcast
        float* nrow = nv0r[c & 1] + xl * TS1;
        float4 A0 = *(const float4*)(xrow + 0);
        float4 A1 = *(const float4*)(xrow + 4);
        float4 B0 = *(const float4*)(xrow + 8);
        float4 B1 = *(const float4*)(xrow + 12);
        for (int tb = 0; tb < S; tb += 16) {
          // ---- steps tb..tb+7 (set A); prefetch A <- tb+16..tb+23
          float xa[8] = {A0.x, A0.y, A0.z, A0.w, A1.x, A1.y, A1.z, A1.w};
          A0 = *(const float4*)(xrow + tb + 16);   // pad-safe (TS0=92)
          A1 = *(const float4*)(xrow + tb + 20);
          float nva[8];
#pragma unroll
          for (int k = 0; k < 8; ++k) {
            float a  = nv0p + xa[k];
            float q0 = nv0p * R3;
            float e  = __builtin_fmaf(-3.0f, q0, nv0p);
            float q  = __builtin_fmaf(e, R3, q0);  // == RN(nv0p/3)
            bool  r  = nv0p >= 1.5f;
            float f  = a - q;
            nv0p = r ? xa[k] : f;
            nva[k] = nv0p;
          }
          float4 wv;
          wv.x = hi4 ? nva[4] : nva[0];
          wv.y = hi4 ? nva[5] : nva[1];
          wv.z = hi4 ? nva[6] : nva[2];
          wv.w = hi4 ? nva[7] : nva[3];
          *(float4*)(nrow + tb + hi4) = wv;
          // ---- steps tb+8..tb+15 (set B); prefetch B <- tb+24..tb+31
          float xbv[8] = {B0.x, B0.y, B0.z, B0.w, B1.x, B1.y, B1.z, B1.w};
          B0 = *(const float4*)(xrow + tb + 24);
          B1 = *(const float4*)(xrow + tb + 28);
          float nvb[8];
#pragma unroll
          for (int k = 0; k < 8; ++k) {
            float a  = nv0p + xbv[k];
            float q0 = nv0p * R3;
            float e  = __builtin_fmaf(-3.0f, q0, nv0p);
            float q  = __builtin_fmaf(e, R3, q0);
            bool  r  = nv0p >= 1.5f;
            float f  = a - q;
            nv0p = r ? xbv[k] : f;
            nvb[k] = nv0p;
          }
          float4 wv2;
          wv2.x = hi4 ? nvb[4] : nvb[0];
          wv2.y = hi4 ? nvb[5] : nvb[1];
          wv2.z = hi4 ? nvb[6] : nvb[2];
          wv2.w = hi4 ? nvb[7] : nvb[3];
          *(float4*)(nrow + tb + 8 + hi4) = wv2;
        }
      }
    } else if (wid == 1) {
      // ---------- L0 reduce (chunk p-2): lane = step, scan 32 neurons ----
      const int c = p - 2;
      if (c >= 0 && c < NCHUNK) {
        const float* nvs = nv0r[c & 1] + lane;     // [n][t]: lane-contiguous
        float m = nvs[0];
        int j = 0;
#pragma unroll 8
        for (int n = 1; n < 32; ++n) {
          float v = nvs[n * TS1];
          bool g = v > m;               // strict: first index kept on ties
          j = g ? n : j;
          m = g ? v : m;
        }
        // lanes >= S read stale rows: finite/NaN-safe, bounded j, never used.
        j0r[c & 1][lane] = (m >= 1.5f) ? (unsigned)j : 32u;  // 32 -> zero col
      }
    } else if (wid == 2) {
      // ---------- L1 update (chunk p-3) ----------
      const int c = p - 3;
      if (c >= 0 && c < NCHUNK) {
        const int S = min(CT, T_TOTAL - c * CT);
        const int jv = (int)j0r[c & 1][lane];
        const float* wrow = w1s + lane * 33;
        float* nrow = nv1r[c & 1] + lane * TS1;
        float hA[8], hB[8];
#pragma unroll
        for (int k = 0; k < 8; ++k) hA[k] = wrow[read_lane_i(jv, k)];
#pragma unroll
        for (int k = 0; k < 8; ++k) hB[k] = wrow[read_lane_i(jv, 8 + k)];
        for (int tb = 0; tb < S; tb += 16) {
          float nva[8];
#pragma unroll
          for (int k = 0; k < 8; ++k) {
            float h = hA[k];
            hA[k] = wrow[read_lane_i(jv, (tb + k + 16) & 63)];  // wrap: dead
            float a = nv1p + h;
            float m = nv1p * R80;
            bool  r = nv1p >= 1.2f;
            float f = a - m;
            nv1p = r ? h : f;
            nva[k] = nv1p;
          }
          float4 w0v = {nva[0], nva[1], nva[2], nva[3]};
          float4 w1v = {nva[4], nva[5], nva[6], nva[7]};
          *(float4*)(nrow + tb) = w0v;
          *(float4*)(nrow + tb + 4) = w1v;
          float nvb[8];
#pragma unroll
          for (int k = 0; k < 8; ++k) {
            float h = hB[k];
            hB[k] = wrow[read_lane_i(jv, (tb + k + 24) & 63)];  // wrap: dead
            float a = nv1p + h;
            float m = nv1p * R80;
            bool  r = nv1p >= 1.2f;
            float f = a - m;
            nv1p = r ? h : f;
            nvb[k] = nv1p;
          }
          float4 w2v = {nvb[0], nvb[1], nvb[2], nvb[3]};
          float4 w3v = {nvb[4], nvb[5], nvb[6], nvb[7]};
          *(float4*)(nrow + tb + 8) = w2v;
          *(float4*)(nrow + tb + 12) = w3v;
        }
      }
    } else if (wid == 3 || wid == 6) {
      // ---------- L1 reduce (chunk p-4): lane = step, neuron half-scan ----
      const int c = p - 4;
      if (c >= 0 && c < NCHUNK) {
        const int half = (wid == 6) ? 1 : 0;
        const float* nvs = nv1r[c & 1] + half * 32 * TS1 + lane;
        float m = nvs[0];
        int j = 0;
#pragma unroll 8
        for (int n = 1; n < 32; ++n) {
          float v = nvs[n * TS1];
          bool g = v > m;
          j = g ? n : j;
          m = g ? v : m;
        }
        mpr[c & 1][half][lane] = m;
        jpr[c & 1][half][lane] = j;
      }
    } else if (wid == 4) {
      // ---------- loader: x chunk p -> xs [ch][t], dwordx4 in+out ----------
      const int c = p;
      if (c < NCHUNK) {
        float* dst = xs[c & 1];
        const int g4 = lane >> 4;            // channel sub-index 0..3
        const int tl = (lane & 15) << 2;     // local t: 0,4,...,60
        const int tg = c * CT + tl;          // global t of first element
        const bool ok = (tg + 3) < T_TOTAL;  // all-4 valid (T_TOTAL % 4 == 0)
        const int tgs = ok ? tg : 0;         // clamped, always in-bounds
        float4 vr[8];
        // Phase A: 8 independent 16B loads, back-to-back in flight.
#pragma unroll
        for (int g = 0; g < 8; ++g) {
          const int k = g * 4 + g4;
          vr[g] = *reinterpret_cast<const float4*>(&xb[(size_t)k * T_TOTAL + tgs]);
        }
        // Phase B: 8 ds_write_b128, min-time bank pattern (TS0=92).
        const float4 z4 = {0.f, 0.f, 0.f, 0.f};
#pragma unroll
        for (int g = 0; g < 8; ++g) {
          const int k = g * 4 + g4;
          *(float4*)(&dst[k * TS0 + tl]) = ok ? vr[g] : z4;
        }
      }
    } else {
      // ---------- L2 update (chunk p-5): w5 rows 0-63, w7 rows 64-127 ----
      const int c = p - 5;
      if (c >= 0 && c < NCHUNK) {
        const int S = min(CT, T_TOTAL - c * CT);
        // merge L1 partials per-lane (lane = step); tie -> low half = first idx
        float mlo = mpr[c & 1][0][lane], mhi = mpr[c & 1][1][lane];
        int jlo = jpr[c & 1][0][lane], jhi = jpr[c & 1][1][lane];
        bool g = mhi > mlo;
        float mm = g ? mhi : mlo;
        int jj = g ? (jhi + 32) : jlo;
        const int pkv = (mm >= 1.2f) ? jj : 64;          // 64 -> zero col
        const float* wrow = w2s + (lane + ((wid == 7) ? 64 : 0)) * 65;
        float hA[8], hB[8];
#pragma unroll
        for (int k = 0; k < 8; ++k) hA[k] = wrow[read_lane_i(pkv, k)];
#pragma unroll
        for (int k = 0; k < 8; ++k) hB[k] = wrow[read_lane_i(pkv, 8 + k)];
        for (int tb = 0; tb < S; tb += 16) {
#pragma unroll
          for (int k = 0; k < 8; ++k) {
            float h = hA[k];
            hA[k] = wrow[read_lane_i(pkv, (tb + k + 16) & 63)];  // wrap: dead
            float a = nv2p + h;
            float m = nv2p * R80;
            bool  r = nv2p >= 1.2f;
            float f = a - m;
            nv2p = r ? h : f;
          }
#pragma unroll
          for (int k = 0; k < 8; ++k) {
            float h = hB[k];
            hB[k] = wrow[read_lane_i(pkv, (tb + k + 24) & 63)];  // wrap: dead
            float a = nv2p + h;
            float m = nv2p * R80;
            bool  r = nv2p >= 1.2f;
            float f = a - m;
            nv2p = r ? h : f;
          }
        }
      }
    }
    __syncthreads();  // wave-uniform branches: all 8 waves always arrive
  }

  // nv2p is the pre-reset membrane of the last step == pre_v2.
  if (wid == 5) out[(size_t)b * N2 + lane] = expf(nv2p);
  if (wid == 7) out[(size_t)b * N2 + 64 + lane] = expf(nv2p);
}

extern "C" void kernel_launch(void* const* d_in, const int* in_sizes, int n_in,
                              void* d_out, int out_size, void* d_ws, size_t ws_size,
                              hipStream_t stream) {
  (void)n_in; (void)out_size; (void)d_ws; (void)ws_size;
  const float* x = (const float*)d_in[0];
  const float* W1 = (const float*)d_in[1];
  const float* W2 = (const float*)d_in[2];
  float* out = (float*)d_out;
  const int B = in_sizes[0] / (NCH * T_TOTAL);  // 256
  lsm_kernel<<<dim3(B), dim3(512), 0, stream>>>(x, W1, W2, out);
}